// Round 6
// baseline (966.425 us; speedup 1.0000x reference)
//
#include <hip/hip_runtime.h>

#define B_  2
#define S_  2048
#define NH_ 32
#define HD_ 128
#define H_  4096
#define H3_ 12288

typedef __bf16 bf16x8 __attribute__((ext_vector_type(8)));
typedef float  f32x4  __attribute__((ext_vector_type(4)));

__device__ __forceinline__ unsigned short f2bf(float f) {
  unsigned int u = __float_as_uint(f);
  u += 0x7fffu + ((u >> 16) & 1u);
  return (unsigned short)(u >> 16);
}
__device__ __forceinline__ void unpack8(uint4 r, float f[8]) {
  f[0] = __uint_as_float(r.x << 16); f[1] = __uint_as_float(r.x & 0xffff0000u);
  f[2] = __uint_as_float(r.y << 16); f[3] = __uint_as_float(r.y & 0xffff0000u);
  f[4] = __uint_as_float(r.z << 16); f[5] = __uint_as_float(r.z & 0xffff0000u);
  f[6] = __uint_as_float(r.w << 16); f[7] = __uint_as_float(r.w & 0xffff0000u);
}
__device__ __forceinline__ void gload_lds16(const void* g, void* l) {
  __builtin_amdgcn_global_load_lds(
      (const __attribute__((address_space(1))) unsigned int*)g,
      (__attribute__((address_space(3))) unsigned int*)l, 16, 0, 0);
}

#define BARSCHED() do { __builtin_amdgcn_s_barrier(); __builtin_amdgcn_sched_barrier(0); } while (0)

// ---------------- f32 -> bf16 convert ----------------
__global__ __launch_bounds__(256) void cvt_bf16(const float* __restrict__ in,
                                                unsigned short* __restrict__ out,
                                                long n) {
  long i = ((long)blockIdx.x * 256 + threadIdx.x) * 4;
  const long stride = (long)gridDim.x * 256 * 4;
  for (; i < n; i += stride) {
    float4 v = *(const float4*)(in + i);
    ushort4 o;
    o.x = f2bf(v.x); o.y = f2bf(v.y); o.z = f2bf(v.z); o.w = f2bf(v.w);
    *(ushort4*)(out + i) = o;
  }
}

// =============================================================================
// 256x256-tile bf16 GEMM, C[m][n] = sum_k A[m][k]*Bt[n][k]
// 8-phase schedule (m201-style): BK=64, 2-buffer LDS (128 KB), 4 sub-phases
// per K-tile of {ds_read subtile || 2x gload_lds quarter prefetch -> barrier ->
// 16 MFMA -> barrier}, counted vmcnt(4) twice per K-tile (never 0 steady-state),
// T2 chunk-XOR swizzle, T5 setprio.
// LDS regions per buffer (elems): A-kh0 @0, B-kh0 @8192, A-kh1 @16384, B-kh1 @24576.
// EPI 0: bf16 out + bias ; EPI 1: f32 out + bias + residual
// =============================================================================
template <int EPI>
__global__ __launch_bounds__(512, 2) void gemm256(
    const unsigned short* __restrict__ A, const unsigned short* __restrict__ Bt,
    void* __restrict__ C, const float* __restrict__ bias, const float* __restrict__ Res,
    int lda, int ldb, int ldc, int K)
{
  __shared__ __align__(16) unsigned short lds[65536];   // 128 KB = 2 x 64 KB buffers

  const int tid = threadIdx.x;
  const int w = tid >> 6, l = tid & 63;

  // XCD-aware block swizzle (nwg % 8 == 0 at both call sites)
  const int gx = gridDim.x;
  const int nwg = gx * gridDim.y;
  const int flat = blockIdx.y * gx + blockIdx.x;
  const int swz = (flat & 7) * (nwg >> 3) + (flat >> 3);
  const int m0 = (swz / gx) * 256;
  const int n0 = (swz % gx) * 256;

  const int wr = w >> 2, wc = w & 3;      // wave output: rows wr*128.., cols wc*64..
  const int lr16 = l & 15, kq = l >> 4;

  // --- staging: per quarter, thread covers rows tid>>2 and 128+(tid>>2), chunk tid&3.
  // Source chunk pre-swizzled: pc ^ ((row>>1)&3) = (tid&3) ^ ((tid>>3)&3).
  const int strow = tid >> 2;
  const int scs = (((tid & 3) ^ ((tid >> 3) & 3)) << 3);   // elems
  const unsigned short* ga = A  + (long)(m0 + strow) * lda + scs;
  const unsigned short* gb = Bt + (long)(n0 + strow) * ldb + scs;
  const int ldsw = w * 512;               // wave-uniform dest offset within region

  // --- ds_read: logical chunk kq of row rr at physical chunk kq^((rr>>1)&3) ---
  const int rchunk = ((kq ^ ((l >> 1) & 3)) << 3);         // elems
  const int abase = (wr * 128 + lr16) * 32 + rchunk;       // + kh*16384 + mh*2048 + m*512
  const int bbase = 8192 + (wc * 64 + lr16) * 32 + rchunk; // + kh*16384 + n*512

  const int NT = K >> 6;                  // BK = 64

  f32x4 acc[8][4];
  const f32x4 zero = {0.f, 0.f, 0.f, 0.f};
#pragma unroll
  for (int m = 0; m < 8; ++m)
#pragma unroll
    for (int n = 0; n < 4; ++n) acc[m][n] = zero;

  // stage quarter q (0=A-kh0,1=B-kh0,2=A-kh1,3=B-kh1) of K-tile kt into buffer b
  auto stageQ = [&](int kt, int b, int q) {
    const long koff = (long)kt * 64 + (q >> 1) * 32;
    unsigned short* d = lds + b * 32768 + q * 8192 + ldsw;
    if ((q & 1) == 0) {
      gload_lds16(ga + koff,              d);
      gload_lds16(ga + koff + 128L * lda, d + 4096);
    } else {
      gload_lds16(gb + koff,              d);
      gload_lds16(gb + koff + 128L * ldb, d + 4096);
    }
  };

  // prologue: tile 0, all 4 quarters; full drain once (makes in-flight math uniform)
  stageQ(0, 0, 0); stageQ(0, 0, 1); stageQ(0, 0, 2); stageQ(0, 0, 3);
  asm volatile("s_waitcnt vmcnt(0)" ::: "memory");
  BARSCHED();

  bf16x8 av[4], bv[4];
  for (int t = 0; t < NT; ++t) {
    const int cur = t & 1;
    const unsigned short* rb = lds + cur * 32768;
    const int nbuf = cur ^ 1;
    const bool pf = (t + 1 < NT);

    // ---- phase 0: kh0, m-frags 0-3 (reads bv kh0) ----
#pragma unroll
    for (int n = 0; n < 4; ++n) bv[n] = *(const bf16x8*)&rb[bbase + n * 512];
#pragma unroll
    for (int m = 0; m < 4; ++m) av[m] = *(const bf16x8*)&rb[abase + m * 512];
    if (pf) stageQ(t + 1, nbuf, 0);
    BARSCHED();
    __builtin_amdgcn_s_setprio(1);
#pragma unroll
    for (int m = 0; m < 4; ++m)
#pragma unroll
      for (int n = 0; n < 4; ++n)
        acc[m][n] = __builtin_amdgcn_mfma_f32_16x16x32_bf16(av[m], bv[n], acc[m][n], 0, 0, 0);
    __builtin_amdgcn_s_setprio(0);
    BARSCHED();

    // ---- phase 1: kh0, m-frags 4-7 (bv reused) ----
#pragma unroll
    for (int m = 0; m < 4; ++m) av[m] = *(const bf16x8*)&rb[abase + 2048 + m * 512];
    if (pf) stageQ(t + 1, nbuf, 1);
    BARSCHED();
    __builtin_amdgcn_s_setprio(1);
#pragma unroll
    for (int m = 0; m < 4; ++m)
#pragma unroll
      for (int n = 0; n < 4; ++n)
        acc[4 + m][n] = __builtin_amdgcn_mfma_f32_16x16x32_bf16(av[m], bv[n], acc[4 + m][n], 0, 0, 0);
    __builtin_amdgcn_s_setprio(0);
    // boundary: phases 2,3 read kh1 (staged during prev tile ph2,3);
    // allowed outstanding = this tile's q0,q1 prefetch (4 loads)
    if (pf) asm volatile("s_waitcnt vmcnt(4)" ::: "memory");
    else    asm volatile("s_waitcnt vmcnt(0)" ::: "memory");
    BARSCHED();

    // ---- phase 2: kh1, m-frags 0-3 (reads bv kh1) ----
#pragma unroll
    for (int n = 0; n < 4; ++n) bv[n] = *(const bf16x8*)&rb[16384 + bbase + n * 512];
#pragma unroll
    for (int m = 0; m < 4; ++m) av[m] = *(const bf16x8*)&rb[16384 + abase + m * 512];
    if (pf) stageQ(t + 1, nbuf, 2);
    BARSCHED();
    __builtin_amdgcn_s_setprio(1);
#pragma unroll
    for (int m = 0; m < 4; ++m)
#pragma unroll
      for (int n = 0; n < 4; ++n)
        acc[m][n] = __builtin_amdgcn_mfma_f32_16x16x32_bf16(av[m], bv[n], acc[m][n], 0, 0, 0);
    __builtin_amdgcn_s_setprio(0);
    BARSCHED();

    // ---- phase 3: kh1, m-frags 4-7 ----
#pragma unroll
    for (int m = 0; m < 4; ++m) av[m] = *(const bf16x8*)&rb[16384 + abase + 2048 + m * 512];
    if (pf) stageQ(t + 1, nbuf, 3);
    BARSCHED();
    __builtin_amdgcn_s_setprio(1);
#pragma unroll
    for (int m = 0; m < 4; ++m)
#pragma unroll
      for (int n = 0; n < 4; ++n)
        acc[4 + m][n] = __builtin_amdgcn_mfma_f32_16x16x32_bf16(av[m], bv[n], acc[4 + m][n], 0, 0, 0);
    __builtin_amdgcn_s_setprio(0);
    // boundary: next tile ph0,1 read its kh0 (staged this tile ph0,1);
    // allowed outstanding = this tile's q2,q3 prefetch (4 loads)
    if (pf) {
      asm volatile("s_waitcnt vmcnt(4)" ::: "memory");
      BARSCHED();
    }
  }

  // epilogue: C/D layout col=lane&15, row=(lane>>4)*4+i
#pragma unroll
  for (int m = 0; m < 8; ++m) {
    const int grow0 = m0 + wr * 128 + m * 16 + kq * 4;
#pragma unroll
    for (int n = 0; n < 4; ++n) {
      const int gcol = n0 + wc * 64 + n * 16 + lr16;
#pragma unroll
      for (int i = 0; i < 4; ++i) {
        const long gi = (long)(grow0 + i) * ldc + gcol;
        float v = acc[m][n][i];
        if (EPI == 0) {
          ((unsigned short*)C)[gi] = f2bf(v + bias[gcol]);
        } else {
          ((float*)C)[gi] = v + bias[gcol] + Res[gi];
        }
      }
    }
  }
}

// ---------------- 128-tile bf16 GEMM (batched Z-GEMM), swizzled ----------
template <int EPI>
__global__ __launch_bounds__(256) void gemm_bt(
    const unsigned short* __restrict__ Abase, const unsigned short* __restrict__ Bbase,
    void* __restrict__ Cbase, const float* __restrict__ bias, const float* __restrict__ Res,
    int lda, int ldb, int ldc, int K,
    long sAb, long sAn, long sBb, long sBn, long sCb, long sCn)
{
  __shared__ __align__(16) unsigned short As[128][32];
  __shared__ __align__(16) unsigned short Bs[128][32];

  const int zz = blockIdx.z;
  const int zb = zz >> 5, zn = zz & 31;
  const unsigned short* A  = Abase + (long)zb * sAb + (long)zn * sAn;
  const unsigned short* Bm = Bbase + (long)zb * sBb + (long)zn * sBn;
  const long coff = (long)zb * sCb + (long)zn * sCn;

  const int m0 = blockIdx.y * 128;
  const int n0 = blockIdx.x * 128;
  const int tid = threadIdx.x;
  const int wave = tid >> 6;
  const int lane = tid & 63;
  const int wr = wave >> 1, wc = wave & 1;
  const int lr = lane & 15, kq = lane >> 4;
  const int srow = wave * 16 + (lane >> 2);
  const int scol = (((lane & 3) ^ ((lane >> 3) & 3)) << 3);
  const int rch  = ((kq ^ ((lane >> 1) & 3)) << 3);

  const f32x4 zero = {0.0f, 0.0f, 0.0f, 0.0f};
  f32x4 acc[4][4];
#pragma unroll
  for (int m = 0; m < 4; ++m)
#pragma unroll
    for (int n = 0; n < 4; ++n) acc[m][n] = zero;

  for (int k0 = 0; k0 < K; k0 += 32) {
    const unsigned short* ga = A  + (long)(m0 + srow) * lda + k0 + scol;
    const unsigned short* gb = Bm + (long)(n0 + srow) * ldb + k0 + scol;
    gload_lds16(ga,                   &As[wave * 16][0]);
    gload_lds16(ga + (long)64 * lda,  &As[64 + wave * 16][0]);
    gload_lds16(gb,                   &Bs[wave * 16][0]);
    gload_lds16(gb + (long)64 * ldb,  &Bs[64 + wave * 16][0]);
    __syncthreads();

    bf16x8 av[4], bv[4];
#pragma unroll
    for (int m = 0; m < 4; ++m) av[m] = *(const bf16x8*)&As[wr * 64 + m * 16 + lr][rch];
#pragma unroll
    for (int n = 0; n < 4; ++n) bv[n] = *(const bf16x8*)&Bs[wc * 64 + n * 16 + lr][rch];
#pragma unroll
    for (int m = 0; m < 4; ++m)
#pragma unroll
      for (int n = 0; n < 4; ++n)
        acc[m][n] = __builtin_amdgcn_mfma_f32_16x16x32_bf16(av[m], bv[n], acc[m][n], 0, 0, 0);
    __syncthreads();
  }

#pragma unroll
  for (int m = 0; m < 4; ++m) {
    const int grow0 = m0 + wr * 64 + m * 16 + kq * 4;
#pragma unroll
    for (int n = 0; n < 4; ++n) {
      const int gcol = n0 + wc * 64 + n * 16 + lr;
#pragma unroll
      for (int r = 0; r < 4; ++r) {
        const long gi = coff + (long)(grow0 + r) * ldc + gcol;
        float v = acc[m][n][r];
        if (EPI == 0) {
          ((unsigned short*)Cbase)[gi] = f2bf(v + bias[gcol]);
        } else if (EPI == 1) {
          ((float*)Cbase)[gi] = v + bias[gcol] + Res[gi];
        } else {
          ((unsigned short*)Cbase)[gi] = f2bf(v);
        }
      }
    }
  }
}

// ---------------- G = Q^T Q per (b,n), chunked over s, atomic reduce ----------
__global__ __launch_bounds__(256) void compute_g(const unsigned short* __restrict__ fused,
                                                 float* __restrict__ G)
{
  __shared__ float Qs[64][128];
  const int z = blockIdx.x;            // b*32+n
  const int b = z >> 5, n = z & 31;
  const unsigned short* Q = fused + (long)b * S_ * H3_ + n * 384;
  const int t = threadIdx.x;
  const int t1 = t >> 4, t2 = t & 15;
  float acc[8][8];
#pragma unroll
  for (int a = 0; a < 8; ++a)
#pragma unroll
    for (int c = 0; c < 8; ++c) acc[a][c] = 0.f;

  const int sbeg = blockIdx.y * 512;
  for (int s0 = sbeg; s0 < sbeg + 512; s0 += 64) {
#pragma unroll
    for (int ii = 0; ii < 4; ++ii) {
      const int r = ii * 16 + t1;
      float f[8];
      unpack8(*(const uint4*)(Q + (long)(s0 + r) * H3_ + t2 * 8), f);
#pragma unroll
      for (int j = 0; j < 8; ++j) Qs[r][t2 * 8 + j] = f[j];
    }
    __syncthreads();
    for (int ss = 0; ss < 64; ++ss) {
      float qa[8], qb[8];
#pragma unroll
      for (int j = 0; j < 8; ++j) { qa[j] = Qs[ss][t1 * 8 + j]; qb[j] = Qs[ss][t2 * 8 + j]; }
#pragma unroll
      for (int a = 0; a < 8; ++a)
#pragma unroll
        for (int c = 0; c < 8; ++c) acc[a][c] += qa[a] * qb[c];
    }
    __syncthreads();
  }
  float* Gz = G + (long)z * 16384;
#pragma unroll
  for (int a = 0; a < 8; ++a)
#pragma unroll
    for (int c = 0; c < 8; ++c)
      atomicAdd(&Gz[(t1 * 8 + a) * 128 + t2 * 8 + c], acc[a][c]);
}

// ---------------- register-resident Gauss-Jordan inverse of SPD 128x128 ------
__global__ __launch_bounds__(1024) void invert_g(const float* __restrict__ G,
                                                 unsigned short* __restrict__ Ginv)
{
  __shared__ __align__(16) float prow[2][128];
  __shared__ __align__(16) float pcol[2][128];
  const int z = blockIdx.x;
  const int t = threadIdx.x;
  const int c  = t & 127;
  const int rg = t >> 7;                 // 0..7 -> rows rg*16 .. rg*16+15
  const float* Gz = G + (long)z * 16384;

  float a[16];
#pragma unroll
  for (int i = 0; i < 16; ++i) a[i] = Gz[(rg * 16 + i) * 128 + c];

  for (int p = 0; p < 128; ++p) {
    const int buf = p & 1;
    const int prg = p >> 4, pi = p & 15;
    if (rg == prg) {
      float v = a[0];
#pragma unroll
      for (int i = 1; i < 16; ++i) v = (pi == i) ? a[i] : v;
      prow[buf][c] = v;
    }
    if (c == p) {
#pragma unroll
      for (int q = 0; q < 4; ++q) {
        float4 w4 = make_float4(a[q * 4], a[q * 4 + 1], a[q * 4 + 2], a[q * 4 + 3]);
        *(float4*)&pcol[buf][rg * 16 + q * 4] = w4;
      }
    }
    __syncthreads();
    const float invp = 1.0f / prow[buf][p];
    const float rowv = (c == p) ? invp : prow[buf][c] * invp;
#pragma unroll
    for (int q = 0; q < 4; ++q) {
      const float4 pc4 = *(const float4*)&pcol[buf][rg * 16 + q * 4];
      const float pcv[4] = {pc4.x, pc4.y, pc4.z, pc4.w};
#pragma unroll
      for (int j = 0; j < 4; ++j) {
        const int i = q * 4 + j;
        const int r = rg * 16 + i;
        const float cur = (c == p) ? 0.f : a[i];
        a[i] = (r == p) ? rowv : cur - pcv[j] * rowv;
      }
    }
  }
  unsigned short* Oz = Ginv + (long)z * 16384;
#pragma unroll
  for (int i = 0; i < 16; ++i) Oz[(rg * 16 + i) * 128 + c] = f2bf(a[i]);
}

// ---------------- per-position 32x32 head attention ----------------
__global__ __launch_bounds__(256) void attn_pos(
    const unsigned short* __restrict__ fused, const unsigned short* __restrict__ Zb,
    const float* __restrict__ alibi, unsigned short* __restrict__ ctx)
{
  __shared__ __align__(16) unsigned short qkv[H3_];
  __shared__ __align__(16) unsigned short zsh[H_];
  __shared__ float wsh[NH_][NH_ + 1];
  __shared__ float pden[NH_];
  __shared__ float alib[NH_];

  const int s = blockIdx.x, b = blockIdx.y;
  const int t = threadIdx.x;
  const unsigned short* src = fused + ((long)b * S_ + s) * H3_;
  for (int i = t * 8; i < H3_; i += 2048) *(uint4*)&qkv[i] = *(const uint4*)&src[i];
  const unsigned short* zsrc = Zb + ((long)b * S_ + s) * H_;
  for (int i = t * 8; i < H_; i += 2048) *(uint4*)&zsh[i] = *(const uint4*)&zsrc[i];
  if (t < NH_) alib[t] = 0.08838834764831845f * alibi[((long)(b * NH_ + t)) * S_ + s];
  __syncthreads();

  const int i = t >> 3;
  const int j0 = (t & 7) * 4;
  const int rot = (i ^ (t & 7)) & 15;
  float aqk[4] = {0.f, 0.f, 0.f, 0.f};
  float aqz[4] = {0.f, 0.f, 0.f, 0.f};
  for (int dbi = 0; dbi < 16; ++dbi) {
    const int d0b = ((dbi + rot) & 15) * 8;
    float qf[8];
    unpack8(*(const uint4*)&qkv[i * 384 + d0b], qf);
#pragma unroll
    for (int jj = 0; jj < 4; ++jj) {
      const int j = j0 + jj;
      float kf[8], zf[8];
      unpack8(*(const uint4*)&qkv[j * 384 + 128 + d0b], kf);
      unpack8(*(const uint4*)&zsh[j * 128 + d0b], zf);
#pragma unroll
      for (int d = 0; d < 8; ++d) { aqk[jj] += qf[d] * kf[d]; aqz[jj] += qf[d] * zf[d]; }
    }
  }
#pragma unroll
  for (int jj = 0; jj < 4; ++jj)
    wsh[i][j0 + jj] = 0.0078125f * aqk[jj] + alib[j0 + jj] * aqz[jj];
  __syncthreads();

  if (t < NH_) {
    float m = -1e30f;
    for (int j = 0; j < NH_; ++j) m = fmaxf(m, wsh[t][j]);
    float ssum = 0.f;
    for (int j = 0; j < NH_; ++j) { float e = __expf(wsh[t][j] - m); wsh[t][j] = e; ssum += e; }
    pden[t] = 1.0f / (ssum + 1e-8f);
  }
  __syncthreads();

  const int d0 = (t & 7) * 16;
  float acc[16];
#pragma unroll
  for (int d = 0; d < 16; ++d) acc[d] = 0.f;
  for (int j = 0; j < NH_; ++j) {
    const float p = wsh[i][j];
    float vf[16];
    unpack8(*(const uint4*)&qkv[j * 384 + 256 + d0], vf);
    unpack8(*(const uint4*)&qkv[j * 384 + 256 + d0 + 8], vf + 8);
#pragma unroll
    for (int d = 0; d < 16; ++d) acc[d] += p * vf[d];
  }
  const float inv = pden[i];
  union { uint4 u[2]; unsigned short us[16]; } ov;
#pragma unroll
  for (int d = 0; d < 16; ++d) ov.us[d] = f2bf(acc[d] * inv);
  unsigned short* cp = ctx + ((long)b * S_ + s) * H_ + i * HD_ + d0;
  *(uint4*)&cp[0] = ov.u[0];
  *(uint4*)&cp[8] = ov.u[1];
}

// -----------------------------------------------------------------------------
extern "C" void kernel_launch(void* const* d_in, const int* in_sizes, int n_in,
                              void* d_out, int out_size, void* d_ws, size_t ws_size,
                              hipStream_t stream)
{
  (void)in_sizes; (void)n_in; (void)out_size; (void)ws_size;
  const float* hidden   = (const float*)d_in[0];
  const float* residual = (const float*)d_in[1];
  const float* alibi    = (const float*)d_in[2];
  const float* Wqkv     = (const float*)d_in[4];
  const float* bqkv     = (const float*)d_in[5];
  const float* Wd       = (const float*)d_in[6];
  const float* bd       = (const float*)d_in[7];
  float* out = (float*)d_out;

  char* ws = (char*)d_ws;
  size_t off = 0;
  auto carve = [&](size_t bytes) -> void* {
    void* p = ws + off;
    off += (bytes + 255) & ~(size_t)255;
    return p;
  };
  const long nHid = (long)B_ * S_ * H_;
  const long nWq  = (long)H3_ * H_;
  unsigned short* hid_bf   = (unsigned short*)carve((size_t)nHid * 2);
  unsigned short* wqkv_bf  = (unsigned short*)carve((size_t)nWq * 2);
  unsigned short* wd_bf    = (unsigned short*)carve((size_t)H_ * H_ * 2);
  unsigned short* fused_bf = (unsigned short*)carve((size_t)B_ * S_ * H3_ * 2);
  unsigned short* z_bf     = (unsigned short*)carve((size_t)nHid * 2);
  unsigned short* ctx_bf   = (unsigned short*)carve((size_t)nHid * 2);
  float*          Gbuf     = (float*)carve((size_t)64 * 16384 * 4);
  unsigned short* ginv_bf  = (unsigned short*)carve((size_t)64 * 16384 * 2);

  // 1) bf16 casts
  cvt_bf16<<<2048, 256, 0, stream>>>(hidden, hid_bf, nHid);
  cvt_bf16<<<2048, 256, 0, stream>>>(Wqkv, wqkv_bf, nWq);
  cvt_bf16<<<2048, 256, 0, stream>>>(Wd, wd_bf, (long)H_ * H_);

  // 2) fused = hidden @ Wqkv^T + b_qkv  (bf16 out) — 8-phase 256² GEMM
  gemm256<0><<<dim3(H3_ / 256, (B_ * S_) / 256, 1), 512, 0, stream>>>(
      hid_bf, wqkv_bf, fused_bf, bqkv, nullptr, H_, H_, H3_, H_);

  // 3) G = Q^T Q per (b,n); then Ginv via register-resident Gauss-Jordan
  hipMemsetAsync(Gbuf, 0, (size_t)64 * 16384 * 4, stream);
  compute_g<<<dim3(64, 4), 256, 0, stream>>>(fused_bf, Gbuf);
  invert_g<<<64, 1024, 0, stream>>>(Gbuf, ginv_bf);

  // 4) Z[b,s,n,:] = Ginv_{b,n} q_{b,n}(s)   (small batched GEMM, 128² kernel)
  gemm_bt<2><<<dim3(1, S_ / 128, 64), 256, 0, stream>>>(
      fused_bf, ginv_bf, z_bf, nullptr, nullptr, H3_, HD_, H_, HD_,
      (long)S_ * H3_, 384, (long)32 * 16384, 16384, (long)S_ * H_, HD_);

  // 5) per-position 32x32 head attention -> ctx (bf16)
  attn_pos<<<dim3(S_, B_), 256, 0, stream>>>(fused_bf, z_bf, alibi, ctx_bf);

  // 6) out = ctx @ Wd^T + b_dense + residual  (f32 out) — 8-phase 256² GEMM
  gemm256<1><<<dim3(H_ / 256, (B_ * S_) / 256, 1), 512, 0, stream>>>(
      ctx_bf, wd_bf, out, bd, residual, H_, H_, H_, H_);
}